// Round 6
// baseline (61.513 us; speedup 1.0000x reference)
//
#include <hip/hip_runtime.h>

// ---------------- constants ----------------
constexpr int kH = 192, kW = 256, kHW = kH * kW;
constexpr int kFH = 48, kFW = 64, kFHW = kFH * kFW;
constexpr int kMH = 39, kMW = 51;
constexpr int kL = kMH * kMW;          // 1989
constexpr int kLP = 2048;              // padded q length
constexpr int kHeads = 32;
constexpr float kInitH = 256.0f / 5.0f; // init_h = W/INIT_SCALE
constexpr float kInitW = 192.0f / 5.0f; // init_w = H/INIT_SCALE
constexpr float kL2E = 1.44269504088896340736f;
constexpr float kBias = -16.0f;        // log2-domain bias (cancels in n/den)
// pad q (kL..kLP): K=0 -> e = 2^kBias exactly; V=(-1,-1). Analytic removal:
constexpr float kPadCorr = 59.0f / 65536.0f;   // 59 * 2^-16, exact in fp32

typedef float v2f __attribute__((ext_vector_type(2)));
__device__ __forceinline__ v2f pkfma(v2f a, v2f b, v2f c) {
  return __builtin_elementwise_fma(a, b, c);
}

// raw hardware exp2: args in [-40, 0] — no denormal/range fixup needed.
__device__ __forceinline__ float fast_exp2(float x) {
#if __has_builtin(__builtin_amdgcn_exp2f)
  return __builtin_amdgcn_exp2f(x);
#else
  float r;
  asm("v_exp_f32 %0, %1\n\ts_nop 1" : "=v"(r) : "v"(x));
  return r;
#endif
}

struct HeadParams {
  int use;
  int ntop_c, nleft_c, nh_c, nw_c, dy1_c, dx1_c;   // ntop = new_top = max(top,0)
  int ntop_p, nleft_p, nh_p, nw_p, dy1_p, dx1_p;
  float h_c, w_c, h_p, w_p;
};

__device__ __forceinline__ float sigf(float x) { return 1.0f / (1.0f + __expf(-x)); }
__device__ __forceinline__ float stepH(int j) { return (float)(2 * abs(j - 19) + 1); }
__device__ __forceinline__ float stepW(int j) { return (float)(2 * abs(j - 25) + 1); }

__device__ void headParams(int i, const int* clm, const int* plm, const float* sp, HeadParams& h) {
  int ccx = clm[2 * i], ccy = clm[2 * i + 1];
  int pcx = plm[2 * i], pcy = plm[2 * i + 1];
  h.use = !(((ccx == 0) && (ccy == 0)) || ((pcx == 0) && (pcy == 0)));
  {
    int top = ccy - (kMH + 1) / 2, bottom = ccy + kMH / 2;
    int left = ccx - (kMW + 1) / 2, right = ccx + kMW / 2;
    int dy1 = max(-top, 0), dy2 = max(bottom - kH, 0);
    int dx1 = max(-left, 0), dx2 = max(right - kW, 0);
    h.ntop_c = top + dy1; h.nleft_c = left + dx1; h.dy1_c = dy1; h.dx1_c = dx1;
    h.nh_c = max(kMH - dy1 - dy2, 0); h.nw_c = max(kMW - dx1 - dx2, 0);
  }
  {
    int top = pcy - (kMH + 1) / 2, bottom = pcy + kMH / 2;
    int left = pcx - (kMW + 1) / 2, right = pcx + kMW / 2;
    int dy1 = max(-top, 0), dy2 = max(bottom - kH, 0);
    int dx1 = max(-left, 0), dx2 = max(right - kW, 0);
    h.ntop_p = top + dy1; h.nleft_p = left + dx1; h.dy1_p = dy1; h.dx1_p = dx1;
    h.nh_p = max(kMH - dy1 - dy2, 0); h.nw_p = max(kMW - dx1 - dx2, 0);
  }
  float adj_cw = sp[4 * i + 0], adj_ch = sp[4 * i + 1];
  float adj_pw = sp[4 * i + 2], adj_ph = sp[4 * i + 3];
  h.h_c = kInitH * sigf(adj_ch);
  h.w_c = kInitW * sigf(adj_cw);
  h.h_p = kInitH * sigf(adj_ph);
  h.w_p = kInitW * sigf(adj_pw);
}

// -------- init output: flow = -1, mask = 0 --------
__global__ void k_init(float4* __restrict__ out, int n4, int nflow4) {
  int i = blockIdx.x * 256 + threadIdx.x;
  if (i < n4) {
    float v = (i < nflow4) ? -1.0f : 0.0f;
    out[i] = make_float4(v, v, v, v);
  }
}

// -------- quarter-res prelu + 1x1 conv (64 -> 4 ch) --------
__global__ void k_reduce(const float* __restrict__ fc, const float* __restrict__ fp,
                         const float* __restrict__ w1, const float* __restrict__ b1, const float* __restrict__ a1,
                         const float* __restrict__ w2, const float* __restrict__ b2, const float* __restrict__ a2,
                         float* __restrict__ fr) {
  int gid = blockIdx.x * 256 + threadIdx.x;
  if (gid >= 2 * kFHW) return;
  int which = gid / kFHW;          // block-uniform (kFHW = 3072 = 12*256)
  int pix = gid - which * kFHW;
  const float* f = which ? fp : fc;
  const float* w = which ? w2 : w1;
  const float* b = which ? b2 : b1;
  float a = which ? a2[0] : a1[0];
  float acc0 = 0.f, acc1 = 0.f, acc2 = 0.f, acc3 = 0.f;
  for (int c = 0; c < 64; ++c) {
    float x = f[c * kFHW + pix];
    float pr = fmaxf(x, 0.f) + a * fminf(x, 0.f);
    acc0 = fmaf(pr, w[c], acc0);
    acc1 = fmaf(pr, w[64 + c], acc1);
    acc2 = fmaf(pr, w[128 + c], acc2);
    acc3 = fmaf(pr, w[192 + c], acc3);
  }
  float* o = fr + which * 4 * kFHW;
  o[pix]            = acc0 + b[0];
  o[kFHW + pix]     = acc1 + b[1];
  o[2 * kFHW + pix] = acc2 + b[2];
  o[3 * kFHW + pix] = acc3 + b[3];
}

// -------- materialize planar K (cloth), V (location@cloth), P (person, pre-scaled) --------
// K planes: Kpl[c][i][q] c=0..3, plane stride 32*2048. V planes: Vpl[d][i][q] d=0..1.
__global__ void k_patch(const float* __restrict__ fr, const float* __restrict__ loc,
                        const float* __restrict__ sp, const int* __restrict__ clm, const int* __restrict__ plm,
                        float* __restrict__ Kpl, float* __restrict__ Vpl, float4* __restrict__ Pall) {
  int i = blockIdx.y;
  int q = blockIdx.x * 256 + threadIdx.x;   // q in [0, 2048)
  HeadParams hp; headParams(i, clm, plm, sp, hp);
  int qr = q / kMW, qc = q - qr * kMW;
  constexpr int PS = kHeads * kLP;          // plane stride
  int o = i * kLP + q;
  // c-side -> K, V (pad q >= kL: K=0, V=-1, corrected analytically in merge)
  {
    bool val = (q < kL) && hp.use && (qr < hp.nh_c) && (qc < hp.nw_c);
    int row = min(hp.ntop_c + qr, kH - 1);
    int col = min(hp.nleft_c + qc, kW - 1);
    int mr = min(hp.dy1_c + qr, kMH - 1);
    int mc = min(hp.dx1_c + qc, kMW - 1);
    float mv = sigf((hp.h_c - stepH(mr)) * 2.f) * sigf((hp.w_c - stepW(mc)) * 2.f);
    int fpix = (row >> 2) * kFW + (col >> 2);
    float kx = 0.f, ky = 0.f, kz = 0.f, kw = 0.f, vx = -1.f, vy = -1.f;
    if (val) {
      kx = fr[fpix] * mv;
      ky = fr[kFHW + fpix] * mv;
      kz = fr[2 * kFHW + fpix] * mv;
      kw = fr[3 * kFHW + fpix] * mv;
      vx = loc[(2 * i) * kHW + row * kW + col];
      vy = loc[(2 * i + 1) * kHW + row * kW + col];
    }
    Kpl[o] = kx; Kpl[PS + o] = ky; Kpl[2 * PS + o] = kz; Kpl[3 * PS + o] = kw;
    Vpl[o] = vx; Vpl[PS + o] = vy;
  }
  // p-side -> P (scaled by log2e so exp2 needs no extra multiply)
  if (q < kL) {
    bool val = hp.use && (qr < hp.nh_p) && (qc < hp.nw_p);
    int row = min(hp.ntop_p + qr, kH - 1);
    int col = min(hp.nleft_p + qc, kW - 1);
    int mr = min(hp.dy1_p + qr, kMH - 1);
    int mc = min(hp.dx1_p + qc, kMW - 1);
    float mv = sigf((hp.h_p - stepH(mr)) * 2.f) * sigf((hp.w_p - stepW(mc)) * 2.f) * kL2E;
    int fpix = (row >> 2) * kFW + (col >> 2);
    float4 pv = make_float4(0.f, 0.f, 0.f, 0.f);
    if (val) {
      const float* frp = fr + 4 * kFHW;
      pv.x = frp[fpix] * mv;
      pv.y = frp[kFHW + fpix] * mv;
      pv.z = frp[2 * kFHW + fpix] * mv;
      pv.w = frp[3 * kFHW + fpix] * mv;
    }
    Pall[i * kL + q] = pv;
  }
}

// -------- single-pass partial softmax-attention, packed fp32, 2 p per thread --------
template<int QLEN>
__global__ void __launch_bounds__(256) k_attn_t(const float* __restrict__ Kpl, const float* __restrict__ Vpl,
                                                const float4* __restrict__ Pall,
                                                float* __restrict__ pD, float* __restrict__ pX,
                                                float* __restrict__ pY) {
  constexpr int PS = kHeads * kLP;
  int i = blockIdx.z;
  int qsi = blockIdx.y;
  int p0 = blockIdx.x * 512 + threadIdx.x;
  int p1 = p0 + 256;
  int pe0 = min(p0, kL - 1);
  int pe1 = min(p1, kL - 1);
  const int base = i * kLP + qsi * QLEN;
  const float* kx = Kpl + base;
  const float* ky = Kpl + PS + base;
  const float* kz = Kpl + 2 * PS + base;
  const float* kw = Kpl + 3 * PS + base;
  const float* vx = Vpl + base;
  const float* vy = Vpl + PS + base;
  float4 Pa = Pall[i * kL + pe0];
  float4 Pb = Pall[i * kL + pe1];
  v2f aX = {Pa.x, Pa.x}, aY = {Pa.y, Pa.y}, aZ = {Pa.z, Pa.z}, aW = {Pa.w, Pa.w};
  v2f bX = {Pb.x, Pb.x}, bY = {Pb.y, Pb.y}, bZ = {Pb.z, Pb.z}, bW = {Pb.w, Pb.w};
  const v2f B = {kBias, kBias};
  // accumulators: [p(a/b)][qpair(0/1)]
  v2f da0 = {0.f, 0.f}, da1 = {0.f, 0.f}, db0 = {0.f, 0.f}, db1 = {0.f, 0.f};
  v2f xa0 = {0.f, 0.f}, xa1 = {0.f, 0.f}, xb0 = {0.f, 0.f}, xb1 = {0.f, 0.f};
  v2f ya0 = {0.f, 0.f}, ya1 = {0.f, 0.f}, yb0 = {0.f, 0.f}, yb1 = {0.f, 0.f};
#pragma unroll 4
  for (int t = 0; t < QLEN; t += 4) {
    v2f K0x = *(const v2f*)(kx + t),     K0y = *(const v2f*)(ky + t);
    v2f K0z = *(const v2f*)(kz + t),     K0w = *(const v2f*)(kw + t);
    v2f K1x = *(const v2f*)(kx + t + 2), K1y = *(const v2f*)(ky + t + 2);
    v2f K1z = *(const v2f*)(kz + t + 2), K1w = *(const v2f*)(kw + t + 2);
    v2f V0x = *(const v2f*)(vx + t),     V0y = *(const v2f*)(vy + t);
    v2f V1x = *(const v2f*)(vx + t + 2), V1y = *(const v2f*)(vy + t + 2);
    // dots: p=a/b  x  qpair=0/1
    v2f sa0 = pkfma(aW, K0w, B); sa0 = pkfma(aZ, K0z, sa0); sa0 = pkfma(aY, K0y, sa0); sa0 = pkfma(aX, K0x, sa0);
    v2f sa1 = pkfma(aW, K1w, B); sa1 = pkfma(aZ, K1z, sa1); sa1 = pkfma(aY, K1y, sa1); sa1 = pkfma(aX, K1x, sa1);
    v2f sb0 = pkfma(bW, K0w, B); sb0 = pkfma(bZ, K0z, sb0); sb0 = pkfma(bY, K0y, sb0); sb0 = pkfma(bX, K0x, sb0);
    v2f sb1 = pkfma(bW, K1w, B); sb1 = pkfma(bZ, K1z, sb1); sb1 = pkfma(bY, K1y, sb1); sb1 = pkfma(bX, K1x, sb1);
    v2f ea0 = {fast_exp2(sa0.x), fast_exp2(sa0.y)};
    v2f ea1 = {fast_exp2(sa1.x), fast_exp2(sa1.y)};
    v2f eb0 = {fast_exp2(sb0.x), fast_exp2(sb0.y)};
    v2f eb1 = {fast_exp2(sb1.x), fast_exp2(sb1.y)};
    da0 += ea0; xa0 = pkfma(ea0, V0x, xa0); ya0 = pkfma(ea0, V0y, ya0);
    da1 += ea1; xa1 = pkfma(ea1, V1x, xa1); ya1 = pkfma(ea1, V1y, ya1);
    db0 += eb0; xb0 = pkfma(eb0, V0x, xb0); yb0 = pkfma(eb0, V0y, yb0);
    db1 += eb1; xb1 = pkfma(eb1, V1x, xb1); yb1 = pkfma(eb1, V1y, yb1);
  }
  int oa = (i * gridDim.y + qsi) * kLP + pe0;
  int ob = (i * gridDim.y + qsi) * kLP + pe1;
  pD[oa] = da0.x + da0.y + da1.x + da1.y;
  pX[oa] = xa0.x + xa0.y + xa1.x + xa1.y;
  pY[oa] = ya0.x + ya0.y + ya1.x + ya1.y;
  pD[ob] = db0.x + db0.y + db1.x + db1.y;
  pX[ob] = xb0.x + xb0.y + xb1.x + xb1.y;
  pY[ob] = yb0.x + yb0.y + yb1.x + yb1.y;
}

// -------- merge partials + pad correction + scatter (valid (r,c) unique) --------
__global__ void k_merge(const float* __restrict__ pD, const float* __restrict__ pX, const float* __restrict__ pY,
                        int QS,
                        const float* __restrict__ sp, const int* __restrict__ clm, const int* __restrict__ plm,
                        float* __restrict__ out) {
  int i = blockIdx.y;
  int p = blockIdx.x * 256 + threadIdx.x;
  if (p >= kL) return;
  HeadParams hp; headParams(i, clm, plm, sp, hp);

  int pr = p / kMW, pc = p - pr * kMW;
  bool val = hp.use && (pr < hp.nh_p) && (pc < hp.nw_p);
  if (!val) return;

  float den = -kPadCorr, n0 = kPadCorr, n1 = kPadCorr;  // remove pad-q contribution
  for (int k = 0; k < QS; ++k) {
    int o = (i * QS + k) * kLP + p;
    den += pD[o]; n0 += pX[o]; n1 += pY[o];
  }
  float inv = 1.0f / den;
  float f0 = n0 * inv, f1 = n1 * inv;

  int R = hp.ntop_p + pr;   // <= H-1 guaranteed for valid pr
  int C = hp.nleft_p + pc;  // <= W-1 guaranteed for valid pc
  out[(2 * i) * kHW + R * kW + C] = f0;
  out[(2 * i + 1) * kHW + R * kW + C] = f1;
  out[64 * kHW + i * kHW + R * kW + C] = 1.0f;
}

extern "C" void kernel_launch(void* const* d_in, const int* in_sizes, int n_in,
                              void* d_out, int out_size, void* d_ws, size_t ws_size,
                              hipStream_t stream) {
  (void)in_sizes; (void)n_in;
  const float* loc = (const float*)d_in[0];
  const float* fc  = (const float*)d_in[1];
  const float* fp  = (const float*)d_in[2];
  const float* sp  = (const float*)d_in[3];
  const int* clm   = (const int*)d_in[6];
  const int* plm   = (const int*)d_in[7];
  const float* w1  = (const float*)d_in[8];
  const float* b1  = (const float*)d_in[9];
  const float* a1  = (const float*)d_in[10];
  const float* w2  = (const float*)d_in[11];
  const float* b2  = (const float*)d_in[12];
  const float* a2  = (const float*)d_in[13];
  float* out = (float*)d_out;
  char* ws = (char*)d_ws;

  // workspace layout (16B aligned)
  float*  fr   = (float*)(ws);                 // 98,304 B
  float*  Kpl  = (float*)(ws + 98304);         // 4*32*2048*4 = 1,048,576 B
  float*  Vpl  = (float*)(ws + 1146880);       // 2*32*2048*4 =   524,288 B
  float4* Pall = (float4*)(ws + 1671168);      // 32*1989*16  = 1,018,368 B
  size_t base = 2689536;
  size_t perQS = (size_t)3 * kHeads * kLP * 4; // 786,432 B per q-slice (3 planes)
  int QS = 1;
  if (ws_size >= base + 16 * perQS) QS = 16;
  else if (ws_size >= base + 8 * perQS) QS = 8;
  else if (ws_size >= base + 4 * perQS) QS = 4;
  else if (ws_size >= base + 2 * perQS) QS = 2;
  float* pD = (float*)(ws + base);
  float* pX = pD + (size_t)QS * kHeads * kLP;
  float* pY = pX + (size_t)QS * kHeads * kLP;

  int n4 = out_size / 4;            // 1,179,648 (exactly divisible)
  int nflow4 = 64 * kHW / 4;        //   786,432
  k_init<<<(n4 + 255) / 256, 256, 0, stream>>>((float4*)out, n4, nflow4);
  k_reduce<<<(2 * kFHW + 255) / 256, 256, 0, stream>>>(fc, fp, w1, b1, a1, w2, b2, a2, fr);
  k_patch<<<dim3(kLP / 256, kHeads), 256, 0, stream>>>(fr, loc, sp, clm, plm, Kpl, Vpl, Pall);
  dim3 ag(4, QS, kHeads);           // 2 p per thread: 512 p per block
  switch (QS) {
    case 16: k_attn_t<128><<<ag, 256, 0, stream>>>(Kpl, Vpl, Pall, pD, pX, pY); break;
    case 8:  k_attn_t<256><<<ag, 256, 0, stream>>>(Kpl, Vpl, Pall, pD, pX, pY); break;
    case 4:  k_attn_t<512><<<ag, 256, 0, stream>>>(Kpl, Vpl, Pall, pD, pX, pY); break;
    case 2:  k_attn_t<1024><<<ag, 256, 0, stream>>>(Kpl, Vpl, Pall, pD, pX, pY); break;
    default: k_attn_t<2048><<<ag, 256, 0, stream>>>(Kpl, Vpl, Pall, pD, pX, pY); break;
  }
  k_merge<<<dim3((kL + 255) / 256, kHeads), 256, 0, stream>>>(pD, pX, pY, QS, sp, clm, plm, out);
}

// Round 7
// 57.030 us; speedup vs baseline: 1.0786x; 1.0786x over previous
//
#include <hip/hip_runtime.h>

// ---------------- constants ----------------
constexpr int kH = 192, kW = 256, kHW = kH * kW;
constexpr int kFH = 48, kFW = 64, kFHW = kFH * kFW;
constexpr int kMH = 39, kMW = 51;
constexpr int kL = kMH * kMW;          // 1989
constexpr int kLP = 2048;              // padded q length
constexpr int kHeads = 32;
constexpr float kInitH = 256.0f / 5.0f; // init_h = W/INIT_SCALE
constexpr float kInitW = 192.0f / 5.0f; // init_w = H/INIT_SCALE
constexpr float kL2E = 1.44269504088896340736f;
constexpr float kBias = -16.0f;        // log2-domain bias (cancels in n/den)
// pad q (kL..kLP): K=0 -> e = 2^kBias exactly; V=(-1,-1). Analytic removal:
constexpr float kPadCorr = 59.0f / 65536.0f;   // 59 * 2^-16, exact in fp32

typedef float v2f __attribute__((ext_vector_type(2)));
__device__ __forceinline__ v2f pkfma(v2f a, v2f b, v2f c) {
  return __builtin_elementwise_fma(a, b, c);
}

// raw hardware exp2: args in [-40, 0] — no denormal/range fixup needed.
__device__ __forceinline__ float fast_exp2(float x) {
#if __has_builtin(__builtin_amdgcn_exp2f)
  return __builtin_amdgcn_exp2f(x);
#else
  float r;
  asm("v_exp_f32 %0, %1\n\ts_nop 1" : "=v"(r) : "v"(x));
  return r;
#endif
}

struct HeadParams {
  int use;
  int ntop_c, nleft_c, nh_c, nw_c, dy1_c, dx1_c;   // ntop = new_top = max(top,0)
  int ntop_p, nleft_p, nh_p, nw_p, dy1_p, dx1_p;
  float h_c, w_c, h_p, w_p;
};

__device__ __forceinline__ float sigf(float x) { return 1.0f / (1.0f + __expf(-x)); }
__device__ __forceinline__ float stepH(int j) { return (float)(2 * abs(j - 19) + 1); }
__device__ __forceinline__ float stepW(int j) { return (float)(2 * abs(j - 25) + 1); }

__device__ void headParams(int i, const int* clm, const int* plm, const float* sp, HeadParams& h) {
  int ccx = clm[2 * i], ccy = clm[2 * i + 1];
  int pcx = plm[2 * i], pcy = plm[2 * i + 1];
  h.use = !(((ccx == 0) && (ccy == 0)) || ((pcx == 0) && (pcy == 0)));
  {
    int top = ccy - (kMH + 1) / 2, bottom = ccy + kMH / 2;
    int left = ccx - (kMW + 1) / 2, right = ccx + kMW / 2;
    int dy1 = max(-top, 0), dy2 = max(bottom - kH, 0);
    int dx1 = max(-left, 0), dx2 = max(right - kW, 0);
    h.ntop_c = top + dy1; h.nleft_c = left + dx1; h.dy1_c = dy1; h.dx1_c = dx1;
    h.nh_c = max(kMH - dy1 - dy2, 0); h.nw_c = max(kMW - dx1 - dx2, 0);
  }
  {
    int top = pcy - (kMH + 1) / 2, bottom = pcy + kMH / 2;
    int left = pcx - (kMW + 1) / 2, right = pcx + kMW / 2;
    int dy1 = max(-top, 0), dy2 = max(bottom - kH, 0);
    int dx1 = max(-left, 0), dx2 = max(right - kW, 0);
    h.ntop_p = top + dy1; h.nleft_p = left + dx1; h.dy1_p = dy1; h.dx1_p = dx1;
    h.nh_p = max(kMH - dy1 - dy2, 0); h.nw_p = max(kMW - dx1 - dx2, 0);
  }
  float adj_cw = sp[4 * i + 0], adj_ch = sp[4 * i + 1];
  float adj_pw = sp[4 * i + 2], adj_ph = sp[4 * i + 3];
  h.h_c = kInitH * sigf(adj_ch);
  h.w_c = kInitW * sigf(adj_cw);
  h.h_p = kInitH * sigf(adj_ph);
  h.w_p = kInitW * sigf(adj_pw);
}

// -------- k_pre: blocks 0..23 = quarter-res prelu+1x1 conv; block 24 = head params --------
__global__ void k_pre(const float* __restrict__ fc, const float* __restrict__ fp,
                      const float* __restrict__ w1, const float* __restrict__ b1, const float* __restrict__ a1,
                      const float* __restrict__ w2, const float* __restrict__ b2, const float* __restrict__ a2,
                      const float* __restrict__ sp, const int* __restrict__ clm, const int* __restrict__ plm,
                      float* __restrict__ fr, int* __restrict__ hpws) {
  int bx = blockIdx.x;
  if (bx == 24) {
    int i = threadIdx.x;
    if (i < kHeads) {
      HeadParams h; headParams(i, clm, plm, sp, h);
      int* o = hpws + i * 20;
      o[0] = h.use;
      o[1] = h.ntop_c; o[2] = h.nleft_c; o[3] = h.nh_c; o[4] = h.nw_c; o[5] = h.dy1_c; o[6] = h.dx1_c;
      o[7] = h.ntop_p; o[8] = h.nleft_p; o[9] = h.nh_p; o[10] = h.nw_p; o[11] = h.dy1_p; o[12] = h.dx1_p;
      o[13] = __float_as_int(h.h_c); o[14] = __float_as_int(h.w_c);
      o[15] = __float_as_int(h.h_p); o[16] = __float_as_int(h.w_p);
    }
    return;
  }
  int gid = bx * 256 + threadIdx.x;   // < 6144 = 2*kFHW
  int which = gid / kFHW;             // block-uniform (kFHW = 3072 = 12*256)
  int pix = gid - which * kFHW;
  const float* f = which ? fp : fc;
  const float* w = which ? w2 : w1;
  const float* b = which ? b2 : b1;
  float a = which ? a2[0] : a1[0];
  float acc0 = 0.f, acc1 = 0.f, acc2 = 0.f, acc3 = 0.f;
  for (int c = 0; c < 64; ++c) {
    float x = f[c * kFHW + pix];
    float pr = fmaxf(x, 0.f) + a * fminf(x, 0.f);
    acc0 = fmaf(pr, w[c], acc0);
    acc1 = fmaf(pr, w[64 + c], acc1);
    acc2 = fmaf(pr, w[128 + c], acc2);
    acc3 = fmaf(pr, w[192 + c], acc3);
  }
  float* o = fr + which * 4 * kFHW;
  o[pix]            = acc0 + b[0];
  o[kFHW + pix]     = acc1 + b[1];
  o[2 * kFHW + pix] = acc2 + b[2];
  o[3 * kFHW + pix] = acc3 + b[3];
}

// -------- materialize planar K (cloth), V (location@cloth), P (person, pre-scaled) --------
// K planes: Kpl[c][i][q] c=0..3, plane stride 32*2048. V planes: Vpl[d][i][q] d=0..1.
__global__ void k_patch(const float* __restrict__ fr, const float* __restrict__ loc,
                        const int* __restrict__ hpws,
                        float* __restrict__ Kpl, float* __restrict__ Vpl, float4* __restrict__ Pall) {
  int i = blockIdx.y;
  int q = blockIdx.x * 256 + threadIdx.x;   // q in [0, 2048)
  const int* hp = hpws + i * 20;            // wave-uniform -> scalar loads
  int use = hp[0];
  int ntop_c = hp[1], nleft_c = hp[2], nh_c = hp[3], nw_c = hp[4], dy1_c = hp[5], dx1_c = hp[6];
  int ntop_p = hp[7], nleft_p = hp[8], nh_p = hp[9], nw_p = hp[10], dy1_p = hp[11], dx1_p = hp[12];
  float h_c = __int_as_float(hp[13]), w_c = __int_as_float(hp[14]);
  float h_p = __int_as_float(hp[15]), w_p = __int_as_float(hp[16]);
  int qr = q / kMW, qc = q - qr * kMW;
  constexpr int PS = kHeads * kLP;          // plane stride
  int o = i * kLP + q;
  // c-side -> K, V (pad q >= kL: K=0, V=-1, corrected analytically in merge)
  {
    bool val = (q < kL) && use && (qr < nh_c) && (qc < nw_c);
    int row = min(ntop_c + qr, kH - 1);
    int col = min(nleft_c + qc, kW - 1);
    int mr = min(dy1_c + qr, kMH - 1);
    int mc = min(dx1_c + qc, kMW - 1);
    float mv = sigf((h_c - stepH(mr)) * 2.f) * sigf((w_c - stepW(mc)) * 2.f);
    int fpix = (row >> 2) * kFW + (col >> 2);
    float kx = 0.f, ky = 0.f, kz = 0.f, kw = 0.f, vx = -1.f, vy = -1.f;
    if (val) {
      kx = fr[fpix] * mv;
      ky = fr[kFHW + fpix] * mv;
      kz = fr[2 * kFHW + fpix] * mv;
      kw = fr[3 * kFHW + fpix] * mv;
      vx = loc[(2 * i) * kHW + row * kW + col];
      vy = loc[(2 * i + 1) * kHW + row * kW + col];
    }
    Kpl[o] = kx; Kpl[PS + o] = ky; Kpl[2 * PS + o] = kz; Kpl[3 * PS + o] = kw;
    Vpl[o] = vx; Vpl[PS + o] = vy;
  }
  // p-side -> P (scaled by log2e so exp2 needs no extra multiply)
  if (q < kL) {
    bool val = use && (qr < nh_p) && (qc < nw_p);
    int row = min(ntop_p + qr, kH - 1);
    int col = min(nleft_p + qc, kW - 1);
    int mr = min(dy1_p + qr, kMH - 1);
    int mc = min(dx1_p + qc, kMW - 1);
    float mv = sigf((h_p - stepH(mr)) * 2.f) * sigf((w_p - stepW(mc)) * 2.f) * kL2E;
    int fpix = (row >> 2) * kFW + (col >> 2);
    float4 pv = make_float4(0.f, 0.f, 0.f, 0.f);
    if (val) {
      const float* frp = fr + 4 * kFHW;
      pv.x = frp[fpix] * mv;
      pv.y = frp[kFHW + fpix] * mv;
      pv.z = frp[2 * kFHW + fpix] * mv;
      pv.w = frp[3 * kFHW + fpix] * mv;
    }
    Pall[i * kL + q] = pv;
  }
}

// -------- single-pass partial softmax-attention, packed fp32, static trip count --------
template<int QLEN>
__global__ void __launch_bounds__(256) k_attn_t(const float* __restrict__ Kpl, const float* __restrict__ Vpl,
                                                const float4* __restrict__ Pall,
                                                float* __restrict__ pD, float* __restrict__ pX,
                                                float* __restrict__ pY) {
  constexpr int PS = kHeads * kLP;
  int i = blockIdx.z;
  int qsi = blockIdx.y;
  int p = blockIdx.x * 249 + threadIdx.x;
  int pe = min(p, kL - 1);
  const int base = i * kLP + qsi * QLEN;
  const float* kx = Kpl + base;
  const float* ky = Kpl + PS + base;
  const float* kz = Kpl + 2 * PS + base;
  const float* kw = Kpl + 3 * PS + base;
  const float* vx = Vpl + base;
  const float* vy = Vpl + PS + base;
  float4 P = Pall[i * kL + pe];
  v2f PX = {P.x, P.x}, PY = {P.y, P.y}, PZ = {P.z, P.z}, PW = {P.w, P.w};
  const v2f B = {kBias, kBias};
  v2f dA = {0.f, 0.f}, dB = {0.f, 0.f};
  v2f xA = {0.f, 0.f}, xB = {0.f, 0.f};
  v2f yA = {0.f, 0.f}, yB = {0.f, 0.f};
#pragma unroll 8
  for (int t = 0; t < QLEN; t += 4) {
    // pair A: q = t, t+1
    v2f sA = pkfma(PW, *(const v2f*)(kw + t), B);
    sA = pkfma(PZ, *(const v2f*)(kz + t), sA);
    sA = pkfma(PY, *(const v2f*)(ky + t), sA);
    sA = pkfma(PX, *(const v2f*)(kx + t), sA);
    // pair B: q = t+2, t+3
    v2f sB = pkfma(PW, *(const v2f*)(kw + t + 2), B);
    sB = pkfma(PZ, *(const v2f*)(kz + t + 2), sB);
    sB = pkfma(PY, *(const v2f*)(ky + t + 2), sB);
    sB = pkfma(PX, *(const v2f*)(kx + t + 2), sB);
    v2f eA = {fast_exp2(sA.x), fast_exp2(sA.y)};
    v2f eB = {fast_exp2(sB.x), fast_exp2(sB.y)};
    dA += eA;
    xA = pkfma(eA, *(const v2f*)(vx + t), xA);
    yA = pkfma(eA, *(const v2f*)(vy + t), yA);
    dB += eB;
    xB = pkfma(eB, *(const v2f*)(vx + t + 2), xB);
    yB = pkfma(eB, *(const v2f*)(vy + t + 2), yB);
  }
  int o = (i * gridDim.y + qsi) * kLP + pe;
  pD[o] = dA.x + dA.y + dB.x + dB.y;
  pX[o] = xA.x + xA.y + xB.x + xB.y;
  pY[o] = yA.x + yA.y + yB.x + yB.y;
}

// -------- full-image merge: init + partial-merge + inverse-map scatter, all coalesced --------
__global__ void k_merge_full(const float* __restrict__ pD, const float* __restrict__ pX,
                             const float* __restrict__ pY, int QS,
                             const int* __restrict__ hpws, float* __restrict__ out) {
  int i = blockIdx.y;
  int pix = blockIdx.x * 256 + threadIdx.x;   // < kHW
  const int* hp = hpws + i * 20;              // wave-uniform -> scalar loads
  int use = hp[0];
  int ntop_p = hp[7], nleft_p = hp[8], nh_p = hp[9], nw_p = hp[10];
  int r = pix >> 8;          // kW = 256
  int c = pix & 255;
  int pr = r - ntop_p, pc = c - nleft_p;
  bool val = use && ((unsigned)pr < (unsigned)nh_p) && ((unsigned)pc < (unsigned)nw_p);
  float f0 = -1.f, f1 = -1.f, mk = 0.f;
  if (val) {
    int p = pr * kMW + pc;
    float den = -kPadCorr, n0 = kPadCorr, n1 = kPadCorr;  // remove pad-q contribution
    for (int k = 0; k < QS; ++k) {
      int o = (i * QS + k) * kLP + p;
      den += pD[o]; n0 += pX[o]; n1 += pY[o];
    }
    float inv = 1.0f / den;
    f0 = n0 * inv; f1 = n1 * inv; mk = 1.0f;
  }
  out[(2 * i) * kHW + pix]      = f0;
  out[(2 * i + 1) * kHW + pix]  = f1;
  out[64 * kHW + i * kHW + pix] = mk;
}

extern "C" void kernel_launch(void* const* d_in, const int* in_sizes, int n_in,
                              void* d_out, int out_size, void* d_ws, size_t ws_size,
                              hipStream_t stream) {
  (void)in_sizes; (void)n_in; (void)out_size;
  const float* loc = (const float*)d_in[0];
  const float* fc  = (const float*)d_in[1];
  const float* fp  = (const float*)d_in[2];
  const float* sp  = (const float*)d_in[3];
  const int* clm   = (const int*)d_in[6];
  const int* plm   = (const int*)d_in[7];
  const float* w1  = (const float*)d_in[8];
  const float* b1  = (const float*)d_in[9];
  const float* a1  = (const float*)d_in[10];
  const float* w2  = (const float*)d_in[11];
  const float* b2  = (const float*)d_in[12];
  const float* a2  = (const float*)d_in[13];
  float* out = (float*)d_out;
  char* ws = (char*)d_ws;

  // workspace layout (16B aligned)
  int*    hpws = (int*)(ws);                   // 32*20*4 = 2560 B (pad to 4096)
  float*  fr   = (float*)(ws + 4096);          // 98,304 B
  float*  Kpl  = (float*)(ws + 102400);        // 4*32*2048*4 = 1,048,576 B
  float*  Vpl  = (float*)(ws + 1150976);       // 2*32*2048*4 =   524,288 B
  float4* Pall = (float4*)(ws + 1675264);      // 32*1989*16  = 1,018,368 B
  size_t base = 2693632;
  size_t perQS = (size_t)3 * kHeads * kLP * 4; // 786,432 B per q-slice (3 planes)
  int QS = 1;
  if (ws_size >= base + 16 * perQS) QS = 16;
  else if (ws_size >= base + 8 * perQS) QS = 8;
  else if (ws_size >= base + 4 * perQS) QS = 4;
  else if (ws_size >= base + 2 * perQS) QS = 2;
  float* pD = (float*)(ws + base);
  float* pX = pD + (size_t)QS * kHeads * kLP;
  float* pY = pX + (size_t)QS * kHeads * kLP;

  k_pre<<<25, 256, 0, stream>>>(fc, fp, w1, b1, a1, w2, b2, a2, sp, clm, plm, fr, hpws);
  k_patch<<<dim3(kLP / 256, kHeads), 256, 0, stream>>>(fr, loc, hpws, Kpl, Vpl, Pall);
  dim3 ag(8, QS, kHeads);
  switch (QS) {
    case 16: k_attn_t<128><<<ag, 256, 0, stream>>>(Kpl, Vpl, Pall, pD, pX, pY); break;
    case 8:  k_attn_t<256><<<ag, 256, 0, stream>>>(Kpl, Vpl, Pall, pD, pX, pY); break;
    case 4:  k_attn_t<512><<<ag, 256, 0, stream>>>(Kpl, Vpl, Pall, pD, pX, pY); break;
    case 2:  k_attn_t<1024><<<ag, 256, 0, stream>>>(Kpl, Vpl, Pall, pD, pX, pY); break;
    default: k_attn_t<2048><<<ag, 256, 0, stream>>>(Kpl, Vpl, Pall, pD, pX, pY); break;
  }
  k_merge_full<<<dim3(kHW / 256, kHeads), 256, 0, stream>>>(pD, pX, pY, QS, hpws, out);
}